// Round 4
// baseline (336.180 us; speedup 1.0000x reference)
//
#include <hip/hip_runtime.h>
#include <stdint.h>

#define BN_EPS 1e-3f

constexpr int Bn = 32, H = 56, W = 56, C = 256;
constexpr int WPC = 8;            // u32 words per 256-channel bit vector
constexpr int HO = 28, WO = 28;   // pooled output dims
constexpr int NW = 72;            // 9 taps * 8 words

// ---------------------------------------------------------------------------
// Binarize x: bit c = (x >= 0). Pack via wave ballot.
__global__ __launch_bounds__(256) void k_binarize_x(const float* __restrict__ x,
                                                    uint32_t* __restrict__ xbits) {
  int i = blockIdx.x * 256 + threadIdx.x;
  float v = x[i];
  unsigned long long m = __ballot(v >= 0.0f);
  if ((threadIdx.x & 63) == 0) {
    ((unsigned long long*)xbits)[i >> 6] = m;
  }
}

// ---------------------------------------------------------------------------
// Binarize weights HWIO [3][3][256 ic][256 oc] -> wbT[oc][j], j = tap*8+word.
__global__ __launch_bounds__(256) void k_binarize_w(const float* __restrict__ w,
                                                    uint32_t* __restrict__ wbT) {
  int j = blockIdx.x;        // 0..71
  int oc = threadIdx.x;      // 0..255
  int tap = j >> 3, ww = j & 7;
  const float* base = w + ((size_t)(tap * C) + ww * 32) * C + oc;
  uint32_t bits = 0;
#pragma unroll
  for (int b = 0; b < 32; ++b) {
    float v = base[(size_t)b * C];
    bits |= (v >= 0.0f ? 1u : 0u) << b;
  }
  wbT[(size_t)oc * NW + j] = bits;
}

// ---------------------------------------------------------------------------
__device__ __forceinline__ void corr3(const int* pw, bool rv0, bool rv2,
                                      int& cI, int& cL, int& cR) {
  int nvI = 0, pvI = 0, nvL = 0, pvL = 0, nvR = 0, pvR = 0;
#pragma unroll
  for (int ky = 0; ky < 3; ++ky) {
    bool rvk = (ky == 0) ? rv0 : ((ky == 2) ? rv2 : true);
#pragma unroll
    for (int kx = 0; kx < 3; ++kx) {
      int p = pw[ky * 3 + kx];
      if (rvk) nvI++; else pvI += p;
      if (rvk && kx != 0) nvL++; else pvL += p;
      if (rvk && kx != 2) nvR++; else pvR += p;
    }
  }
  cI = 256 * nvI + 2 * pvI;
  cL = 256 * nvL + 2 * pvL;
  cR = 256 * nvR + 2 * pvR;
}

// ct1[oc][0..8]: conv1 integer thresholds T = (corr - ceil(t1)) >> 1 for row
// cases {int, top, bot} x col {I,L,R}; [9] = sub0 (popc of all kx=0 weights).
// ct2[oc][0..8]: conv2 raw corr values, same order; [9] = sub0.
__global__ __launch_bounds__(256) void k_prep(
    const uint32_t* __restrict__ wb1, const uint32_t* __restrict__ wb2,
    const float* __restrict__ beta1, const float* __restrict__ mean1,
    const float* __restrict__ var1, const float* __restrict__ beta2,
    const float* __restrict__ mean2, const float* __restrict__ var2,
    int* __restrict__ ct1, int* __restrict__ ct2,
    float* __restrict__ a2t, float* __restrict__ b2t) {
  int oc = threadIdx.x;
  {
    int* ct = ct1 + oc * 10;
    int pw[9];
#pragma unroll
    for (int t = 0; t < 9; ++t) {
      int acc = 0;
#pragma unroll
      for (int w = 0; w < 8; ++w) acc += __popc(wb1[(size_t)oc * NW + t * 8 + w]);
      pw[t] = acc;
    }
    float t1 = mean1[oc] - beta1[oc] * sqrtf(var1[oc] + BN_EPS);
    int it1 = (int)ceilf(t1);
    int c[9];
    corr3(pw, true, true, c[0], c[1], c[2]);
    corr3(pw, false, true, c[3], c[4], c[5]);
    corr3(pw, true, false, c[6], c[7], c[8]);
#pragma unroll
    for (int k = 0; k < 9; ++k) ct[k] = (c[k] - it1) >> 1;
    ct[9] = pw[0] + pw[3] + pw[6];
  }
  {
    int* ct = ct2 + oc * 10;
    int pw[9];
#pragma unroll
    for (int t = 0; t < 9; ++t) {
      int acc = 0;
#pragma unroll
      for (int w = 0; w < 8; ++w) acc += __popc(wb2[(size_t)oc * NW + t * 8 + w]);
      pw[t] = acc;
    }
    corr3(pw, true, true, ct[0], ct[1], ct[2]);
    corr3(pw, false, true, ct[3], ct[4], ct[5]);
    corr3(pw, true, false, ct[6], ct[7], ct[8]);
    ct[9] = pw[0] + pw[3] + pw[6];
  }
  float s2 = rsqrtf(var2[oc] + BN_EPS);
  a2t[oc] = s2;
  b2t[oc] = beta2[oc] - mean2[oc] * s2;
}

// ---------------------------------------------------------------------------
// Per-lane row load: lane owns one column's 8 bit-words; zeros outside.
__device__ __forceinline__ void load_row(const uint32_t* __restrict__ bits, int b,
                                         int rr, int c, uint32_t* X) {
  if (rr >= 0 && rr < H && c < W) {
    const uint32_t* p = bits + (((size_t)b * H + rr) * W + c) * WPC;
    uint4 a = *(const uint4*)p;
    uint4 d = *(const uint4*)(p + 4);
    X[0] = a.x; X[1] = a.y; X[2] = a.z; X[3] = a.w;
    X[4] = d.x; X[5] = d.y; X[6] = d.z; X[7] = d.w;
  } else {
#pragma unroll
    for (int k = 0; k < 8; ++k) X[k] = 0;
  }
}

// Stage this block's 32-oc weight slab + ct table into LDS.
__device__ __forceinline__ void stage_wct(const uint32_t* __restrict__ wbT,
                                          const int* __restrict__ ctab, int ocbase,
                                          uint32_t* sW, int* sCT) {
  const uint32_t* gw = wbT + (size_t)ocbase * NW;
  for (int t = threadIdx.x; t < 32 * NW; t += 128) sW[t] = gw[t];
  for (int t = threadIdx.x; t < 32 * 12; t += 128) {
    int ol = t / 12, j = t - ol * 12;
    sCT[t] = (j < 10) ? ctab[(ocbase + ol) * 10 + j] : 0;
  }
}

// 4-row XOR-popcount core: per-kx partial popcounts q0/q1/q2 for output rows
// r0..r0+3 from X[6][8], weights read from LDS (uniform-address broadcast).
#define QBODY4(wl)                                                        \
  int q0[4] = {0, 0, 0, 0}, q1[4] = {0, 0, 0, 0}, q2[4] = {0, 0, 0, 0};   \
  _Pragma("unroll") for (int ky = 0; ky < 3; ++ky) {                      \
    uint32_t wk[24];                                                      \
    _Pragma("unroll") for (int j = 0; j < 6; ++j)                         \
        *(uint4*)&wk[4 * j] = ((const uint4*)((wl) + ky * 24))[j];        \
    _Pragma("unroll") for (int w = 0; w < 8; ++w) {                       \
      const uint32_t w0 = wk[w], w1 = wk[8 + w], w2 = wk[16 + w];         \
      _Pragma("unroll") for (int i = 0; i < 4; ++i) {                     \
        const uint32_t x = X[i + ky][w];                                  \
        q0[i] += __popc(x ^ w0);                                          \
        q1[i] += __popc(x ^ w1);                                          \
        q2[i] += __popc(x ^ w2);                                          \
      }                                                                   \
    }                                                                     \
  }

// ---------------------------------------------------------------------------
// Conv1 (XNOR) + BN1 + sign -> packed bits. Wave = 4 rows, block = 2 waves.
__global__ __launch_bounds__(128) void k_conv1(
    const uint32_t* __restrict__ xbits, const uint32_t* __restrict__ wbT,
    const int* __restrict__ ctab, uint32_t* __restrict__ hbits) {
  const int lane = threadIdx.x & 63;
  const int wid = threadIdx.x >> 6;
  const int b = blockIdx.y;
  const int z = blockIdx.z;
  const int ocbase = z * 32;

  __shared__ __align__(16) uint32_t sW[32 * NW];
  __shared__ __align__(16) int sCT[32 * 12];
  stage_wct(wbT, ctab, ocbase, sW, sCT);
  __syncthreads();

  const int qh = __builtin_amdgcn_readfirstlane(blockIdx.x * 2 + wid);  // 0..13
  const int r0 = qh * 4;
  const int c = lane;

  uint32_t X[6][8];
#pragma unroll
  for (int i = 0; i < 6; ++i) load_row(xbits, b, r0 - 1 + i, c, X[i]);

  uint32_t bits[4] = {0, 0, 0, 0};

  for (int ocl = 0; ocl < 32; ++ocl) {
    const uint32_t* wl = &sW[ocl * NW];
    int cr[12];
#pragma unroll
    for (int j = 0; j < 3; ++j)
      *(int4*)&cr[4 * j] = ((const int4*)&sCT[ocl * 12])[j];

    QBODY4(wl)

    const int sub0 = cr[9];
#pragma unroll
    for (int i = 0; i < 4; ++i) {
      int u0 = __shfl_up(q0[i], 1);
      int d2 = __shfl_down(q2[i], 1);
      if (lane == 0) u0 = sub0;
      const int P = u0 + q1[i] + d2;
      const int r = r0 + i;
      int tI = cr[0], tL = cr[1], tR = cr[2];
      if (r == 0)          { tI = cr[3]; tL = cr[4]; tR = cr[5]; }
      else if (r == H - 1) { tI = cr[6]; tL = cr[7]; tR = cr[8]; }
      const int T = (lane == 0) ? tL : ((lane == W - 1) ? tR : tI);
      bits[i] |= (uint32_t)((P <= T) ? 1u : 0u) << ocl;
    }
  }
  if (c < W) {
    size_t base = (((size_t)b * H + r0) * W + c) * WPC + z;
#pragma unroll
    for (int i = 0; i < 4; ++i) hbits[base + (size_t)i * (W * WPC)] = bits[i];
  }
}

// ---------------------------------------------------------------------------
// Conv2 (XNOR) + 2x2 maxpool + BN2 -> f32. Wave = 2 pooled rows (4 conv rows).
__global__ __launch_bounds__(128) void k_conv2(
    const uint32_t* __restrict__ hbits, const uint32_t* __restrict__ wbT,
    const int* __restrict__ ctab, const float* __restrict__ a2t,
    const float* __restrict__ b2t, float* __restrict__ out) {
  const int lane = threadIdx.x & 63;
  const int wid = threadIdx.x >> 6;
  const int b = blockIdx.y;
  const int z = blockIdx.z;
  const int ocbase = z * 32;

  __shared__ __align__(16) uint32_t sW[32 * NW];
  __shared__ __align__(16) int sCT[32 * 12];
  __shared__ float sA2[32], sB2[32];
  stage_wct(wbT, ctab, ocbase, sW, sCT);
  if (threadIdx.x < 32) sA2[threadIdx.x] = a2t[ocbase + threadIdx.x];
  else if (threadIdx.x < 64) sB2[threadIdx.x - 32] = b2t[ocbase + threadIdx.x - 32];
  __syncthreads();

  const int qh = __builtin_amdgcn_readfirstlane(blockIdx.x * 2 + wid);  // 0..13
  const int r0 = qh * 4;
  const int c = lane;

  uint32_t X[6][8];
#pragma unroll
  for (int i = 0; i < 6; ++i) load_row(hbits, b, r0 - 1 + i, c, X[i]);

  const bool writer = ((lane & 1) == 0) && (lane < W);
  float* p0 = out + (((size_t)b * HO + 2 * qh) * WO + (lane >> 1)) * C + ocbase;
  float* p1 = p0 + (size_t)WO * C;

  for (int g = 0; g < 8; ++g) {
    float o0[4], o1[4];
#pragma unroll
    for (int k = 0; k < 4; ++k) {
      const int ocl = g * 4 + k;
      const uint32_t* wl = &sW[ocl * NW];
      int cr[12];
#pragma unroll
      for (int j = 0; j < 3; ++j)
        *(int4*)&cr[4 * j] = ((const int4*)&sCT[ocl * 12])[j];

      QBODY4(wl)

      const int sub0 = cr[9];
      int d[4];
#pragma unroll
      for (int i = 0; i < 4; ++i) {
        int u0 = __shfl_up(q0[i], 1);
        int d2 = __shfl_down(q2[i], 1);
        if (lane == 0) u0 = sub0;
        const int P = u0 + q1[i] + d2;
        const int r = r0 + i;
        int cI = cr[0], cL = cr[1], cRv = cr[2];
        if (r == 0)          { cI = cr[3]; cL = cr[4]; cRv = cr[5]; }
        else if (r == H - 1) { cI = cr[6]; cL = cr[7]; cRv = cr[8]; }
        const int corr = (lane == 0) ? cL : ((lane == W - 1) ? cRv : cI);
        d[i] = corr - 2 * P;
      }
      int m0 = max(d[0], d[1]); m0 = max(m0, __shfl_xor(m0, 1));
      int m1 = max(d[2], d[3]); m1 = max(m1, __shfl_xor(m1, 1));
      o0[k] = (float)m0 * sA2[ocl] + sB2[ocl];
      o1[k] = (float)m1 * sA2[ocl] + sB2[ocl];
    }
    if (writer) {
      *(float4*)(p0 + g * 4) = make_float4(o0[0], o0[1], o0[2], o0[3]);
      *(float4*)(p1 + g * 4) = make_float4(o1[0], o1[1], o1[2], o1[3]);
    }
  }
}

// ---------------------------------------------------------------------------
extern "C" void kernel_launch(void* const* d_in, const int* in_sizes, int n_in,
                              void* d_out, int out_size, void* d_ws, size_t ws_size,
                              hipStream_t stream) {
  const float* x     = (const float*)d_in[0];
  const float* w1    = (const float*)d_in[1];
  const float* beta1 = (const float*)d_in[2];
  const float* mean1 = (const float*)d_in[3];
  const float* var1  = (const float*)d_in[4];
  const float* w2    = (const float*)d_in[5];
  const float* beta2 = (const float*)d_in[6];
  const float* mean2 = (const float*)d_in[7];
  const float* var2  = (const float*)d_in[8];
  float* out = (float*)d_out;

  uint32_t* ws32 = (uint32_t*)d_ws;
  const size_t XBW = (size_t)Bn * H * W * WPC;  // 802816 u32
  uint32_t* xbits = ws32;
  uint32_t* hbits = xbits + XBW;
  uint32_t* wb1   = hbits + XBW;
  uint32_t* wb2   = wb1 + (size_t)C * NW;
  int* ct1        = (int*)(wb2 + (size_t)C * NW);
  int* ct2        = ct1 + C * 10;
  float* a2t      = (float*)(ct2 + C * 10);
  float* b2t      = a2t + C;

  k_binarize_x<<<dim3((Bn * H * W * C) / 256), 256, 0, stream>>>(x, xbits);
  k_binarize_w<<<dim3(NW), 256, 0, stream>>>(w1, wb1);
  k_binarize_w<<<dim3(NW), 256, 0, stream>>>(w2, wb2);
  k_prep<<<dim3(1), 256, 0, stream>>>(wb1, wb2, beta1, mean1, var1,
                                      beta2, mean2, var2, ct1, ct2, a2t, b2t);
  k_conv1<<<dim3(7, Bn, 8), 128, 0, stream>>>(xbits, wb1, ct1, hbits);
  k_conv2<<<dim3(7, Bn, 8), 128, 0, stream>>>(hbits, wb2, ct2, a2t, b2t, out);
}

// Round 5
// 333.067 us; speedup vs baseline: 1.0093x; 1.0093x over previous
//
#include <hip/hip_runtime.h>
#include <stdint.h>

#define BN_EPS 1e-3f

constexpr int Bn = 32, H = 56, W = 56, C = 256;
constexpr int WPC = 8;            // u32 words per 256-channel bit vector
constexpr int HO = 28, WO = 28;   // pooled output dims
constexpr int NW = 72;            // 9 taps * 8 words

// ---------------------------------------------------------------------------
// Binarize x: bit c = (x >= 0). Pack via wave ballot.
__global__ __launch_bounds__(256) void k_binarize_x(const float* __restrict__ x,
                                                    uint32_t* __restrict__ xbits) {
  int i = blockIdx.x * 256 + threadIdx.x;
  float v = x[i];
  unsigned long long m = __ballot(v >= 0.0f);
  if ((threadIdx.x & 63) == 0) {
    ((unsigned long long*)xbits)[i >> 6] = m;
  }
}

// ---------------------------------------------------------------------------
// Binarize weights HWIO [3][3][256 ic][256 oc] -> wbT[oc][j], j = tap*8+word.
__global__ __launch_bounds__(256) void k_binarize_w(const float* __restrict__ w,
                                                    uint32_t* __restrict__ wbT) {
  int j = blockIdx.x;        // 0..71
  int oc = threadIdx.x;      // 0..255
  int tap = j >> 3, ww = j & 7;
  const float* base = w + ((size_t)(tap * C) + ww * 32) * C + oc;
  uint32_t bits = 0;
#pragma unroll
  for (int b = 0; b < 32; ++b) {
    float v = base[(size_t)b * C];
    bits |= (v >= 0.0f ? 1u : 0u) << b;
  }
  wbT[(size_t)oc * NW + j] = bits;
}

// ---------------------------------------------------------------------------
__device__ __forceinline__ void corr3(const int* pw, bool rv0, bool rv2,
                                      int& cI, int& cL, int& cR) {
  int nvI = 0, pvI = 0, nvL = 0, pvL = 0, nvR = 0, pvR = 0;
#pragma unroll
  for (int ky = 0; ky < 3; ++ky) {
    bool rvk = (ky == 0) ? rv0 : ((ky == 2) ? rv2 : true);
#pragma unroll
    for (int kx = 0; kx < 3; ++kx) {
      int p = pw[ky * 3 + kx];
      if (rvk) nvI++; else pvI += p;
      if (rvk && kx != 0) nvL++; else pvL += p;
      if (rvk && kx != 2) nvR++; else pvR += p;
    }
  }
  cI = 256 * nvI + 2 * pvI;
  cL = 256 * nvL + 2 * pvL;
  cR = 256 * nvR + 2 * pvR;
}

// ct1[oc][0..8]: conv1 integer thresholds T = (corr - ceil(t1)) >> 1 for row
// cases {int, top, bot} x col {I,L,R}; [9] = sub0 (popc of all kx=0 weights).
// ct2[oc][0..8]: conv2 raw corr values, same order; [9] = sub0.
__global__ __launch_bounds__(256) void k_prep(
    const uint32_t* __restrict__ wb1, const uint32_t* __restrict__ wb2,
    const float* __restrict__ beta1, const float* __restrict__ mean1,
    const float* __restrict__ var1, const float* __restrict__ beta2,
    const float* __restrict__ mean2, const float* __restrict__ var2,
    int* __restrict__ ct1, int* __restrict__ ct2,
    float* __restrict__ a2t, float* __restrict__ b2t) {
  int oc = threadIdx.x;
  {
    int* ct = ct1 + oc * 10;
    int pw[9];
#pragma unroll
    for (int t = 0; t < 9; ++t) {
      int acc = 0;
#pragma unroll
      for (int w = 0; w < 8; ++w) acc += __popc(wb1[(size_t)oc * NW + t * 8 + w]);
      pw[t] = acc;
    }
    float t1 = mean1[oc] - beta1[oc] * sqrtf(var1[oc] + BN_EPS);
    int it1 = (int)ceilf(t1);
    int c[9];
    corr3(pw, true, true, c[0], c[1], c[2]);
    corr3(pw, false, true, c[3], c[4], c[5]);
    corr3(pw, true, false, c[6], c[7], c[8]);
#pragma unroll
    for (int k = 0; k < 9; ++k) ct[k] = (c[k] - it1) >> 1;
    ct[9] = pw[0] + pw[3] + pw[6];
  }
  {
    int* ct = ct2 + oc * 10;
    int pw[9];
#pragma unroll
    for (int t = 0; t < 9; ++t) {
      int acc = 0;
#pragma unroll
      for (int w = 0; w < 8; ++w) acc += __popc(wb2[(size_t)oc * NW + t * 8 + w]);
      pw[t] = acc;
    }
    corr3(pw, true, true, ct[0], ct[1], ct[2]);
    corr3(pw, false, true, ct[3], ct[4], ct[5]);
    corr3(pw, true, false, ct[6], ct[7], ct[8]);
    ct[9] = pw[0] + pw[3] + pw[6];
  }
  float s2 = rsqrtf(var2[oc] + BN_EPS);
  a2t[oc] = s2;
  b2t[oc] = beta2[oc] - mean2[oc] * s2;
}

// ---------------------------------------------------------------------------
// Per-lane row load: lane owns one column's 8 bit-words; zeros outside.
__device__ __forceinline__ void load_row(const uint32_t* __restrict__ bits, int b,
                                         int rr, int c, uint32_t* X) {
  if (rr >= 0 && rr < H && c < W) {
    const uint32_t* p = bits + (((size_t)b * H + rr) * W + c) * WPC;
    uint4 a = *(const uint4*)p;
    uint4 d = *(const uint4*)(p + 4);
    X[0] = a.x; X[1] = a.y; X[2] = a.z; X[3] = a.w;
    X[4] = d.x; X[5] = d.y; X[6] = d.z; X[7] = d.w;
  } else {
#pragma unroll
    for (int k = 0; k < 8; ++k) X[k] = 0;
  }
}

// Per-kx partial popcounts for rows A (X[0..2]) and B (X[1..3]) for one oc.
// Weights via wave-uniform pointer -> s_load broadcast (SGPR operands).
#define CORE(S, wp)                                                       \
  uint32_t q0A##S = 0, q1A##S = 0, q2A##S = 0;                            \
  uint32_t q0B##S = 0, q1B##S = 0, q2B##S = 0;                            \
  {                                                                       \
    _Pragma("unroll") for (int ky = 0; ky < 3; ++ky) {                    \
      _Pragma("unroll") for (int w = 0; w < 8; ++w) {                     \
        const uint32_t w0 = (wp)[ky * 24 + w];                            \
        const uint32_t w1 = (wp)[ky * 24 + 8 + w];                        \
        const uint32_t w2 = (wp)[ky * 24 + 16 + w];                       \
        const uint32_t xA = X[ky][w], xB = X[ky + 1][w];                  \
        q0A##S += __popc(xA ^ w0); q1A##S += __popc(xA ^ w1);             \
        q2A##S += __popc(xA ^ w2);                                        \
        q0B##S += __popc(xB ^ w0); q1B##S += __popc(xB ^ w1);             \
        q2B##S += __popc(xB ^ w2);                                        \
      }                                                                   \
    }                                                                     \
  }

// Pack rows A,B into 16-bit halves (q <= 768, sums <= 2304: carry-free) and
// issue the two neighbor shuffles for this oc.
#define PACKSHFL(S)                                                       \
  uint32_t u0##S, d2##S, q1p##S;                                          \
  {                                                                       \
    uint32_t pk0 = q0A##S | (q0B##S << 16);                               \
    uint32_t pk2 = q2A##S | (q2B##S << 16);                               \
    u0##S = (uint32_t)__shfl_up((int)pk0, 1);                             \
    d2##S = (uint32_t)__shfl_down((int)pk2, 1);                           \
    q1p##S = q1A##S | (q1B##S << 16);                                     \
  }

// ---------------------------------------------------------------------------
// Conv1 (XNOR) + BN1 + sign -> packed bits. Wave = row pair, 32 oc, 2-oc SWP.
__global__ __launch_bounds__(256) void k_conv1(
    const uint32_t* __restrict__ xbits, const uint32_t* __restrict__ wbT,
    const int* __restrict__ ctab, uint32_t* __restrict__ hbits) {
  const int lane = threadIdx.x & 63;
  const int q = __builtin_amdgcn_readfirstlane(blockIdx.x * 4 + (threadIdx.x >> 6));
  const int b = blockIdx.y;
  const int z = blockIdx.z;
  const int ocbase = z * 32;
  const int rA = 2 * q;
  const int c = lane;
  const bool top = (q == 0), bot = (q == 27);

  uint32_t X[4][8];
#pragma unroll
  for (int i = 0; i < 4; ++i) load_row(xbits, b, rA - 1 + i, c, X[i]);

  uint32_t bitsA = 0, bitsB = 0;

#define EPI1(S, ctA, ctB, s0, sh)                                         \
  {                                                                       \
    uint32_t u0 = u0##S;                                                  \
    if (lane == 0) u0 = (uint32_t)(s0) * 0x10001u;                        \
    uint32_t Pp = u0 + q1p##S + d2##S;                                    \
    int PA = (int)(Pp & 0xffffu), PB = (int)(Pp >> 16);                   \
    int TA = (lane == 0) ? (ctA)[1] : ((lane == W - 1) ? (ctA)[2] : (ctA)[0]); \
    int TB = (lane == 0) ? (ctB)[1] : ((lane == W - 1) ? (ctB)[2] : (ctB)[0]); \
    bitsA |= (uint32_t)((PA <= TA) ? 1u : 0u) << (sh);                    \
    bitsB |= (uint32_t)((PB <= TB) ? 1u : 0u) << (sh);                    \
  }

  for (int ocl = 0; ocl < 32; ocl += 2) {
    const uint32_t* wpa = wbT + (size_t)(ocbase + ocl) * NW;
    const uint32_t* wpb = wpa + NW;
    const int* cta = ctab + (ocbase + ocl) * 10;
    const int* ctb = cta + 10;
    const int* ctaA = cta + (top ? 3 : 0);
    const int* ctaB = cta + (bot ? 6 : 0);
    const int* ctbA = ctb + (top ? 3 : 0);
    const int* ctbB = ctb + (bot ? 6 : 0);

    CORE(a, wpa)
    PACKSHFL(a)
    CORE(b, wpb)          // covers a's shuffle latency
    PACKSHFL(b)
    EPI1(a, ctaA, ctaB, cta[9], ocl)
    EPI1(b, ctbA, ctbB, ctb[9], ocl + 1)
  }
#undef EPI1

  if (c < W) {
    size_t base = (((size_t)b * H + rA) * W + c) * WPC + z;
    hbits[base] = bitsA;
    hbits[base + W * WPC] = bitsB;
  }
}

// ---------------------------------------------------------------------------
// Conv2 (XNOR) + 2x2 maxpool + BN2 -> f32. Wave = one pooled row, 32 oc.
__global__ __launch_bounds__(256) void k_conv2(
    const uint32_t* __restrict__ hbits, const uint32_t* __restrict__ wbT,
    const int* __restrict__ ctab, const float* __restrict__ a2t,
    const float* __restrict__ b2t, float* __restrict__ out) {
  const int lane = threadIdx.x & 63;
  const int ro = __builtin_amdgcn_readfirstlane(blockIdx.x * 4 + (threadIdx.x >> 6));
  const int b = blockIdx.y;
  const int z = blockIdx.z;
  const int ocbase = z * 32;
  const int rA = 2 * ro;
  const int c = lane;
  const bool top = (ro == 0), bot = (ro == 27);

  uint32_t X[4][8];
#pragma unroll
  for (int i = 0; i < 4; ++i) load_row(hbits, b, rA - 1 + i, c, X[i]);

  const bool writer = ((lane & 1) == 0) && (lane < W);
  float* orow = out + (((size_t)b * HO + ro) * WO + (lane >> 1)) * C + ocbase;

#define EPI2(S, cA, cB, s0, tout)                                         \
  {                                                                       \
    uint32_t u0 = u0##S;                                                  \
    if (lane == 0) u0 = (uint32_t)(s0) * 0x10001u;                        \
    uint32_t Pp = u0 + q1p##S + d2##S;                                    \
    int PA = (int)(Pp & 0xffffu), PB = (int)(Pp >> 16);                   \
    int corrA = (lane == 0) ? (cA)[1] : ((lane == W - 1) ? (cA)[2] : (cA)[0]); \
    int corrB = (lane == 0) ? (cB)[1] : ((lane == W - 1) ? (cB)[2] : (cB)[0]); \
    tout = max(corrA - 2 * PA, corrB - 2 * PB);                           \
  }

  for (int g = 0; g < 8; ++g) {
    const int oc0 = ocbase + g * 4;
    int t0, t1, t2, t3;
    {
      const uint32_t* wpa = wbT + (size_t)oc0 * NW;
      const uint32_t* wpb = wpa + NW;
      const int* cta = ctab + oc0 * 10;
      const int* ctb = cta + 10;
      const int* ctaA = cta + (top ? 3 : 0);
      const int* ctaB = cta + (bot ? 6 : 0);
      const int* ctbA = ctb + (top ? 3 : 0);
      const int* ctbB = ctb + (bot ? 6 : 0);
      CORE(a, wpa)
      PACKSHFL(a)
      CORE(b, wpb)
      PACKSHFL(b)
      EPI2(a, ctaA, ctaB, cta[9], t0)
      EPI2(b, ctbA, ctbB, ctb[9], t1)
    }
    {
      const uint32_t* wpa = wbT + (size_t)(oc0 + 2) * NW;
      const uint32_t* wpb = wpa + NW;
      const int* cta = ctab + (oc0 + 2) * 10;
      const int* ctb = cta + 10;
      const int* ctaA = cta + (top ? 3 : 0);
      const int* ctaB = cta + (bot ? 6 : 0);
      const int* ctbA = ctb + (top ? 3 : 0);
      const int* ctbB = ctb + (bot ? 6 : 0);
      CORE(a, wpa)
      PACKSHFL(a)
      CORE(b, wpb)
      PACKSHFL(b)
      EPI2(a, ctaA, ctaB, cta[9], t2)
      EPI2(b, ctbA, ctbB, ctb[9], t3)
    }
    // Pool across the lane pair: issue all 4 shuffles, then combine.
    int x0 = __shfl_xor(t0, 1), x1 = __shfl_xor(t1, 1);
    int x2 = __shfl_xor(t2, 1), x3 = __shfl_xor(t3, 1);
    if (writer) {
      float o0 = (float)max(t0, x0) * a2t[oc0 + 0] + b2t[oc0 + 0];
      float o1 = (float)max(t1, x1) * a2t[oc0 + 1] + b2t[oc0 + 1];
      float o2 = (float)max(t2, x2) * a2t[oc0 + 2] + b2t[oc0 + 2];
      float o3 = (float)max(t3, x3) * a2t[oc0 + 3] + b2t[oc0 + 3];
      *(float4*)(orow + g * 4) = make_float4(o0, o1, o2, o3);
    }
  }
#undef EPI2
}

// ---------------------------------------------------------------------------
extern "C" void kernel_launch(void* const* d_in, const int* in_sizes, int n_in,
                              void* d_out, int out_size, void* d_ws, size_t ws_size,
                              hipStream_t stream) {
  const float* x     = (const float*)d_in[0];
  const float* w1    = (const float*)d_in[1];
  const float* beta1 = (const float*)d_in[2];
  const float* mean1 = (const float*)d_in[3];
  const float* var1  = (const float*)d_in[4];
  const float* w2    = (const float*)d_in[5];
  const float* beta2 = (const float*)d_in[6];
  const float* mean2 = (const float*)d_in[7];
  const float* var2  = (const float*)d_in[8];
  float* out = (float*)d_out;

  uint32_t* ws32 = (uint32_t*)d_ws;
  const size_t XBW = (size_t)Bn * H * W * WPC;  // 802816 u32
  uint32_t* xbits = ws32;
  uint32_t* hbits = xbits + XBW;
  uint32_t* wb1   = hbits + XBW;
  uint32_t* wb2   = wb1 + (size_t)C * NW;
  int* ct1        = (int*)(wb2 + (size_t)C * NW);
  int* ct2        = ct1 + C * 10;
  float* a2t      = (float*)(ct2 + C * 10);
  float* b2t      = a2t + C;

  k_binarize_x<<<dim3((Bn * H * W * C) / 256), 256, 0, stream>>>(x, xbits);
  k_binarize_w<<<dim3(NW), 256, 0, stream>>>(w1, wb1);
  k_binarize_w<<<dim3(NW), 256, 0, stream>>>(w2, wb2);
  k_prep<<<dim3(1), 256, 0, stream>>>(wb1, wb2, beta1, mean1, var1,
                                      beta2, mean2, var2, ct1, ct2, a2t, b2t);
  k_conv1<<<dim3(7, Bn, 8), 256, 0, stream>>>(xbits, wb1, ct1, hbits);
  k_conv2<<<dim3(7, Bn, 8), 256, 0, stream>>>(hbits, wb2, ct2, a2t, b2t, out);
}